// Round 10
// baseline (576.604 us; speedup 1.0000x reference)
//
#include <hip/hip_runtime.h>
#include <hip/hip_bf16.h>

#define N_NODES 20000
#define KADJ 4
#define NEDGE 320000
#define ETOTAL (KADJ * NEDGE)               // 1,280,000
#define IN_DIM_ 1024
#define H_IN_ 256
#define DDIM 128
#define GATE_H_ 128
#define TEMP_ 0.6f
#define M_CLAMP_ 20.0f
#define CSR_TOTAL (KADJ * N_NODES)          // 80000
#define NCOARSE 128
#define QPER (CSR_TOTAL / NCOARSE)          // 625
#define ESTRIDE 12288                       // bucket slot stride (exp fill 10000, sigma~100)
#define TILE_A 4096
#define BINA_NB ((ETOTAL + TILE_A - 1) / TILE_A)  // 313

typedef __attribute__((ext_vector_type(8))) short frag_ab;      // 8 bf16
typedef __attribute__((ext_vector_type(4))) float frag_cd;      // 4 fp32
typedef __attribute__((ext_vector_type(8))) unsigned short us8;

__device__ inline unsigned short f2bf(float f) {
    unsigned int u = __float_as_uint(f);
    u += 0x7FFFu + ((u >> 16) & 1);   // RNE
    return (unsigned short)(u >> 16);
}
__device__ inline float bflo(unsigned int p) { return __uint_as_float(p << 16); }
__device__ inline float bfhi(unsigned int p) { return __uint_as_float(p & 0xffff0000u); }

// async 16B global->LDS (wave-uniform LDS base + lane*16)
__device__ __forceinline__ void gld16(const unsigned short* g, unsigned short* l) {
    __builtin_amdgcn_global_load_lds(
        (const __attribute__((address_space(1))) void*)g,
        (__attribute__((address_space(3))) void*)l, 16, 0, 0);
}

// ---- X fp32 -> bf16 streaming cast ----
__global__ __launch_bounds__(256) void cast_bf16_kernel(
    const float* __restrict__ X, unsigned short* __restrict__ Xb, int n)
{
    int i = (blockIdx.x * 256 + threadIdx.x) * 8;
    if (i >= n) return;
    float4 a = *(const float4*)(X + i), b = *(const float4*)(X + i + 4);
    us8 o;
    o[0] = f2bf(a.x); o[1] = f2bf(a.y); o[2] = f2bf(a.z); o[3] = f2bf(a.w);
    o[4] = f2bf(b.x); o[5] = f2bf(b.y); o[6] = f2bf(b.z); o[7] = f2bf(b.w);
    *(us8*)(Xb + i) = o;
}

// ============== async bf16 MFMA GEMM: C = [relu](A[M,K]_bf16 @ (Bt[N,K]_bf16)^T + bias) =========
__global__ __launch_bounds__(256) void gemm_async_kernel(
    const unsigned short* __restrict__ A, const unsigned short* __restrict__ Bt,
    const float* __restrict__ bias, float* __restrict__ Cf, unsigned short* __restrict__ Cb,
    int M, int N, int K, int do_relu)
{
    __shared__ unsigned short sA[128 * 64];
    __shared__ unsigned short sB[128 * 64];
    int tid = threadIdx.x;
    int tileM = blockIdx.y * 128, tileN = blockIdx.x * 128;
    int w = tid >> 6, lane = tid & 63;
    int wr = (w & 1) * 64, wc = (w >> 1) * 64;
    int fm = lane & 15, fq = lane >> 4;
    int crow = lane >> 3;              // row within 8-row chunk
    int gsw = (lane & 7) ^ crow;       // global granule this lane fetches

    frag_cd acc[4][4] = {};

    for (int k0 = 0; k0 < K; k0 += 64) {
#pragma unroll
        for (int t = 0; t < 4; t++) {
            int chunk = w * 4 + t;
            int row = chunk * 8 + crow;
            const unsigned short* ga = A + (size_t)(tileM + row) * K + k0 + gsw * 8;
            if (tileM + row < M) gld16(ga, &sA[chunk * 512]);
            const unsigned short* gb = Bt + (size_t)(tileN + row) * K + k0 + gsw * 8;
            gld16(gb, &sB[chunk * 512]);
        }
        __syncthreads();
#pragma unroll
        for (int s = 0; s < 2; s++) {
            int sw = ((s * 4 + fq) ^ (fm & 7)) * 8;
            frag_ab af[4], bf[4];
#pragma unroll
            for (int i = 0; i < 4; i++) af[i] = *(const frag_ab*)&sA[(wr + i * 16 + fm) * 64 + sw];
#pragma unroll
            for (int j = 0; j < 4; j++) bf[j] = *(const frag_ab*)&sB[(wc + j * 16 + fm) * 64 + sw];
#pragma unroll
            for (int i = 0; i < 4; i++)
#pragma unroll
                for (int j = 0; j < 4; j++)
                    acc[i][j] = __builtin_amdgcn_mfma_f32_16x16x32_bf16(af[i], bf[j], acc[i][j], 0, 0, 0);
        }
        __syncthreads();
    }
#pragma unroll
    for (int i = 0; i < 4; i++) {
        int row = tileM + wr + i * 16 + fq * 4;
#pragma unroll
        for (int r = 0; r < 4; r++) {
            if (row + r < M) {
#pragma unroll
                for (int j = 0; j < 4; j++) {
                    int col = tileN + wc + j * 16 + fm;
                    float v = acc[i][j][r];
                    if (bias) v += bias[col];
                    if (do_relu) v = fmaxf(v, 0.f);
                    if (Cf) Cf[(size_t)(row + r) * N + col] = v;
                    if (Cb) Cb[(size_t)(row + r) * N + col] = f2bf(v);
                }
            }
        }
    }
}

// ============== fused Z+GH GEMM: A=Hb[M,128], Bt=wzg[256][128] ==============
// blockIdx.x==0: cols 0-127 = Wmsg^T -> Zb bf16 (no bias/relu)
// blockIdx.x==1: cols 128-255 = Wg1h^T -> GH fp32 (+bg1, no relu)
__global__ __launch_bounds__(256) void zg_gemm_kernel(
    const unsigned short* __restrict__ A, const unsigned short* __restrict__ Bt,
    const float* __restrict__ bg1, unsigned short* __restrict__ Zb,
    float* __restrict__ GH, int M)
{
    __shared__ unsigned short sA[128 * 64];
    __shared__ unsigned short sB[128 * 64];
    int tid = threadIdx.x;
    int tileM = blockIdx.y * 128, tileN = blockIdx.x * 128;
    int w = tid >> 6, lane = tid & 63;
    int wr = (w & 1) * 64, wc = (w >> 1) * 64;
    int fm = lane & 15, fq = lane >> 4;
    int crow = lane >> 3;
    int gsw = (lane & 7) ^ crow;

    frag_cd acc[4][4] = {};

    for (int k0 = 0; k0 < DDIM; k0 += 64) {
#pragma unroll
        for (int t = 0; t < 4; t++) {
            int chunk = w * 4 + t;
            int row = chunk * 8 + crow;
            if (tileM + row < M) gld16(A + (size_t)(tileM + row) * DDIM + k0 + gsw * 8, &sA[chunk * 512]);
            gld16(Bt + (size_t)(tileN + row) * DDIM + k0 + gsw * 8, &sB[chunk * 512]);
        }
        __syncthreads();
#pragma unroll
        for (int s = 0; s < 2; s++) {
            int sw = ((s * 4 + fq) ^ (fm & 7)) * 8;
            frag_ab af[4], bf[4];
#pragma unroll
            for (int i = 0; i < 4; i++) af[i] = *(const frag_ab*)&sA[(wr + i * 16 + fm) * 64 + sw];
#pragma unroll
            for (int j = 0; j < 4; j++) bf[j] = *(const frag_ab*)&sB[(wc + j * 16 + fm) * 64 + sw];
#pragma unroll
            for (int i = 0; i < 4; i++)
#pragma unroll
                for (int j = 0; j < 4; j++)
                    acc[i][j] = __builtin_amdgcn_mfma_f32_16x16x32_bf16(af[i], bf[j], acc[i][j], 0, 0, 0);
        }
        __syncthreads();
    }
    int isZ = (blockIdx.x == 0);
#pragma unroll
    for (int i = 0; i < 4; i++) {
        int row = tileM + wr + i * 16 + fq * 4;
#pragma unroll
        for (int r = 0; r < 4; r++) {
            if (row + r < M) {
#pragma unroll
                for (int j = 0; j < 4; j++) {
                    int col = wc + j * 16 + fm;    // local 0..127
                    float v = acc[i][j][r];
                    if (isZ) Zb[(size_t)(row + r) * DDIM + col] = f2bf(v);
                    else     GH[(size_t)(row + r) * GATE_H_ + col] = v + bg1[col];
                }
            }
        }
    }
}

// ============== head GEMM + logits epilogue: logits = relu(Hb@Wh1+bh1) . Wh2 + bh2 ========
__global__ __launch_bounds__(256) void head_gemm_kernel(
    const unsigned short* __restrict__ A, const unsigned short* __restrict__ Bt,
    const float* __restrict__ bh1, const float* __restrict__ Wh2,
    const float* __restrict__ bh2, float* __restrict__ logits, int M)
{
    __shared__ unsigned short sA[128 * 64];
    __shared__ unsigned short sB[128 * 64];
    __shared__ float sred[2][128];
    int tid = threadIdx.x;
    int tileM = blockIdx.x * 128;
    int w = tid >> 6, lane = tid & 63;
    int wr = (w & 1) * 64, wc = (w >> 1) * 64;
    int fm = lane & 15, fq = lane >> 4;
    int crow = lane >> 3;
    int gsw = (lane & 7) ^ crow;

    frag_cd acc[4][4] = {};

    for (int k0 = 0; k0 < DDIM; k0 += 64) {
#pragma unroll
        for (int t = 0; t < 4; t++) {
            int chunk = w * 4 + t;
            int row = chunk * 8 + crow;
            if (tileM + row < M) gld16(A + (size_t)(tileM + row) * DDIM + k0 + gsw * 8, &sA[chunk * 512]);
            gld16(Bt + (size_t)row * DDIM + k0 + gsw * 8, &sB[chunk * 512]);
        }
        __syncthreads();
#pragma unroll
        for (int s = 0; s < 2; s++) {
            int sw = ((s * 4 + fq) ^ (fm & 7)) * 8;
            frag_ab af[4], bf[4];
#pragma unroll
            for (int i = 0; i < 4; i++) af[i] = *(const frag_ab*)&sA[(wr + i * 16 + fm) * 64 + sw];
#pragma unroll
            for (int j = 0; j < 4; j++) bf[j] = *(const frag_ab*)&sB[(wc + j * 16 + fm) * 64 + sw];
#pragma unroll
            for (int i = 0; i < 4; i++)
#pragma unroll
                for (int j = 0; j < 4; j++)
                    acc[i][j] = __builtin_amdgcn_mfma_f32_16x16x32_bf16(af[i], bf[j], acc[i][j], 0, 0, 0);
        }
        __syncthreads();
    }
    float wv[4], bh[4];
#pragma unroll
    for (int j = 0; j < 4; j++) {
        int c = wc + j * 16 + fm;
        wv[j] = Wh2[c];
        bh[j] = bh1[c];
    }
    float part[4][4];
#pragma unroll
    for (int i = 0; i < 4; i++) {
#pragma unroll
        for (int r = 0; r < 4; r++) {
            float p = 0.f;
#pragma unroll
            for (int j = 0; j < 4; j++) {
                float v = fmaxf(acc[i][j][r] + bh[j], 0.f);
                p += v * wv[j];
            }
            part[i][r] = p;
        }
    }
#pragma unroll
    for (int m = 1; m < 16; m <<= 1)
#pragma unroll
        for (int i = 0; i < 4; i++)
#pragma unroll
            for (int r = 0; r < 4; r++)
                part[i][r] += __shfl_xor(part[i][r], m, 64);
    if (fm == 0) {
#pragma unroll
        for (int i = 0; i < 4; i++)
#pragma unroll
            for (int r = 0; r < 4; r++)
                sred[w >> 1][wr + i * 16 + fq * 4 + r] = part[i][r];
    }
    __syncthreads();
    if (tid < 128 && tileM + tid < M)
        logits[tileM + tid] = sred[0][tid] + sred[1][tid] + bh2[0];
}

// ============== gate GEMM: scores[q] = relu(Mb[q]@Wg1m + GH[q>>2] + logdeg[q]*wld) . Wg2 + bg2 ===
__global__ __launch_bounds__(256) void gate_gemm_kernel(
    const unsigned short* __restrict__ Mb, const unsigned short* __restrict__ Bt,
    const float* __restrict__ GH, const float* __restrict__ logdeg,
    const float* __restrict__ wld, const float* __restrict__ Wg2,
    const float* __restrict__ bg2, float* __restrict__ scores)
{
    __shared__ unsigned short sA[128 * 64];
    __shared__ unsigned short sB[128 * 64];
    __shared__ float sred[2][128];
    int tid = threadIdx.x;
    int tile0 = blockIdx.x * 128;
    int w = tid >> 6, lane = tid & 63;
    int wr = (w & 1) * 64, wc = (w >> 1) * 64;
    int fm = lane & 15, fq = lane >> 4;
    int crow = lane >> 3;
    int gsw = (lane & 7) ^ crow;

    frag_cd acc[4][4] = {};

    for (int k0 = 0; k0 < DDIM; k0 += 64) {
#pragma unroll
        for (int t = 0; t < 4; t++) {
            int chunk = w * 4 + t;
            int row = chunk * 8 + crow;
            gld16(Mb + (size_t)(tile0 + row) * DDIM + k0 + gsw * 8, &sA[chunk * 512]);
            gld16(Bt + (size_t)row * DDIM + k0 + gsw * 8, &sB[chunk * 512]);
        }
        __syncthreads();
#pragma unroll
        for (int s = 0; s < 2; s++) {
            int sw = ((s * 4 + fq) ^ (fm & 7)) * 8;
            frag_ab af[4], bf[4];
#pragma unroll
            for (int i = 0; i < 4; i++) af[i] = *(const frag_ab*)&sA[(wr + i * 16 + fm) * 64 + sw];
#pragma unroll
            for (int j = 0; j < 4; j++) bf[j] = *(const frag_ab*)&sB[(wc + j * 16 + fm) * 64 + sw];
#pragma unroll
            for (int i = 0; i < 4; i++)
#pragma unroll
                for (int j = 0; j < 4; j++)
                    acc[i][j] = __builtin_amdgcn_mfma_f32_16x16x32_bf16(af[i], bf[j], acc[i][j], 0, 0, 0);
        }
        __syncthreads();
    }
    float wg2v[4], wldv[4];
#pragma unroll
    for (int j = 0; j < 4; j++) {
        int c = wc + j * 16 + fm;
        wg2v[j] = Wg2[c];
        wldv[j] = wld[c];
    }
    float part[4][4];
#pragma unroll
    for (int i = 0; i < 4; i++) {
#pragma unroll
        for (int r = 0; r < 4; r++) {
            int q = tile0 + wr + i * 16 + fq * 4 + r;
            int n = q >> 2;
            float ld = logdeg[q];
            float p = 0.f;
#pragma unroll
            for (int j = 0; j < 4; j++) {
                int c = wc + j * 16 + fm;
                float v = acc[i][j][r] + GH[(size_t)n * GATE_H_ + c] + ld * wldv[j];
                p += fmaxf(v, 0.f) * wg2v[j];
            }
            part[i][r] = p;
        }
    }
#pragma unroll
    for (int m = 1; m < 16; m <<= 1)
#pragma unroll
        for (int i = 0; i < 4; i++)
#pragma unroll
            for (int r = 0; r < 4; r++)
                part[i][r] += __shfl_xor(part[i][r], m, 64);
    if (fm == 0) {
#pragma unroll
        for (int i = 0; i < 4; i++)
#pragma unroll
            for (int r = 0; r < 4; r++)
                sred[w >> 1][wr + i * 16 + fq * 4 + r] = part[i][r];
    }
    __syncthreads();
    if (tid < 128) scores[tile0 + tid] = sred[0][tid] + sred[1][tid] + bg2[0];
}

// ============== all weight transposes in ONE launch ==========
struct TD { const float* src; unsigned short* dst; int K; int N; };
struct TD10 { TD d[10]; };

__global__ __launch_bounds__(256) void transpose_all_kernel(TD10 descs)
{
    TD t = descs.d[blockIdx.z];
    int n0 = blockIdx.x * 32, k0 = blockIdx.y * 32;
    if (n0 >= t.N || k0 >= t.K) return;
    __shared__ float tile[32][33];
    int tx = threadIdx.x & 31, ty4 = (threadIdx.x >> 5) * 4;
#pragma unroll
    for (int i = 0; i < 4; i++)
        tile[ty4 + i][tx] = t.src[(size_t)(k0 + ty4 + i) * t.N + n0 + tx];
    __syncthreads();
#pragma unroll
    for (int i = 0; i < 4; i++)
        t.dst[(size_t)(n0 + ty4 + i) * t.K + k0 + tx] = f2bf(tile[tx][ty4 + i]);
}

// ================= CSR build: fixed-stride buckets ==========
__global__ __launch_bounds__(256) void binA2_kernel(
    const int* __restrict__ rows, const int* __restrict__ cols,
    int* __restrict__ bcnt, uint2* __restrict__ staging)
{
    __shared__ int hist[NCOARSE], hscan[NCOARSE], lcur[NCOARSE], gbase[NCOARSE];
    __shared__ uint2 pairs[TILE_A];
    int tid = threadIdx.x;
    int base = blockIdx.x * TILE_A;
    int cnt_t = min(TILE_A, ETOTAL - base);

    for (int i = tid; i < NCOARSE; i += 256) hist[i] = 0;
    __syncthreads();

    unsigned int q[16], c[16];
    bool valid[16];
#pragma unroll
    for (int i = 0; i < 16; i++) {
        int loc = i * 256 + tid;
        valid[i] = loc < cnt_t;
        if (valid[i]) {
            int e = base + loc;
            int k = e / NEDGE;
            unsigned int qq = (unsigned int)(k * N_NODES + rows[e]);
            q[i] = qq;
            c[i] = (unsigned int)cols[e];
            atomicAdd(&hist[qq / QPER], 1);
        }
    }
    __syncthreads();
    if (tid < NCOARSE) hscan[tid] = hist[tid];
    __syncthreads();
    for (int d = 1; d < NCOARSE; d <<= 1) {
        int v = (tid >= d && tid < NCOARSE) ? hscan[tid - d] : 0;
        __syncthreads();
        if (tid < NCOARSE) hscan[tid] += v;
        __syncthreads();
    }
    if (tid < NCOARSE) {
        int ex = hscan[tid] - hist[tid];
        hscan[tid] = ex;
        lcur[tid] = ex;
        gbase[tid] = hist[tid] ? (tid * ESTRIDE + atomicAdd(&bcnt[tid], hist[tid])) : 0;
    }
    __syncthreads();
#pragma unroll
    for (int i = 0; i < 16; i++) {
        if (valid[i]) {
            int b = q[i] / QPER;
            int p = atomicAdd(&lcur[b], 1);
            pairs[p] = make_uint2(q[i], c[i]);
        }
    }
    __syncthreads();
    for (int i = tid; i < cnt_t; i += 256) {
        uint2 pr = pairs[i];
        int b = pr.x / QPER;
        staging[gbase[b] + (i - hscan[b])] = pr;
    }
}

__global__ __launch_bounds__(256) void binB2_kernel(
    const uint2* __restrict__ staging, const int* __restrict__ bcnt,
    int* __restrict__ offs, int* __restrict__ ends, int* __restrict__ edst)
{
    __shared__ int cntS[QPER], sofs[QPER], lcur[QPER];
    __shared__ int psum[256];
    int tid = threadIdx.x, b = blockIdx.x;
    int q0 = b * QPER, base = b * ESTRIDE;
    int fill = bcnt[b];
    for (int i = tid; i < QPER; i += 256) cntS[i] = 0;
    __syncthreads();
    for (int i = tid; i < fill; i += 256)
        atomicAdd(&cntS[staging[base + i].x - q0], 1);
    __syncthreads();
    const int CH = 3;
    int lo = tid * CH, hi = min(lo + CH, QPER);
    int s = 0;
    for (int i = lo; i < hi; i++) s += cntS[i];
    psum[tid] = s;
    __syncthreads();
    for (int d = 1; d < 256; d <<= 1) {
        int v = (tid >= d) ? psum[tid - d] : 0;
        __syncthreads();
        psum[tid] += v;
        __syncthreads();
    }
    int run = (tid == 0) ? 0 : psum[tid - 1];
    for (int i = lo; i < hi; i++) {
        sofs[i] = run;
        lcur[i] = run;
        run += cntS[i];
    }
    __syncthreads();
    for (int i = tid; i < QPER; i += 256) {
        offs[q0 + i] = base + sofs[i];
        ends[q0 + i] = base + sofs[i] + cntS[i];
    }
    for (int i = tid; i < fill; i += 256) {
        uint2 p = staging[base + i];
        int pos = atomicAdd(&lcur[p.x - q0], 1);
        edst[base + pos] = (int)p.y;
    }
}

// ---------------- gather (feature-split, edge-pair): pass p covers elems [p*64, p*64+64) ------
// One wave per q. Lanes 0-31: even edges; lanes 32-63: odd edges. Lane loads 1 dword (2 bf16)
// of the half-row. 4-pair unroll = 8 x 128B loads in flight. Cross-group shfl_xor(32) combine.
__global__ __launch_bounds__(256) void gather_kernel(
    const int* __restrict__ offs, const int* __restrict__ ends,
    const int* __restrict__ edst,
    const unsigned short* __restrict__ Zb, unsigned short* __restrict__ Mb, int pass)
{
    int tid = threadIdx.x;
    int q = blockIdx.x * 4 + (tid >> 6);           // wave id = q
    int lane = tid & 63;
    int grp = lane >> 5;                           // 0: even edges, 1: odd
    int l32 = lane & 31;
    int feat = pass * 64 + l32 * 2;                // bf16 element index
    int k = q / N_NODES;
    int r = q - k * N_NODES;
    int start = offs[q];
    int end = ends[q];
    float ax = 0.f, ay = 0.f;
    int i = start + grp;
    for (; i + 6 < end; i += 8) {
        int c0 = edst[i], c1 = edst[i + 2], c2 = edst[i + 4], c3 = edst[i + 6];
        unsigned int p0 = *(const unsigned int*)(Zb + (size_t)c0 * DDIM + feat);
        unsigned int p1 = *(const unsigned int*)(Zb + (size_t)c1 * DDIM + feat);
        unsigned int p2 = *(const unsigned int*)(Zb + (size_t)c2 * DDIM + feat);
        unsigned int p3 = *(const unsigned int*)(Zb + (size_t)c3 * DDIM + feat);
        ax += bflo(p0) + bflo(p1) + bflo(p2) + bflo(p3);
        ay += bfhi(p0) + bfhi(p1) + bfhi(p2) + bfhi(p3);
    }
    for (; i < end; i += 2) {
        unsigned int p = *(const unsigned int*)(Zb + (size_t)edst[i] * DDIM + feat);
        ax += bflo(p); ay += bfhi(p);
    }
    ax += __shfl_xor(ax, 32, 64);
    ay += __shfl_xor(ay, 32, 64);
    if (grp == 0) {
        ax = fminf(fmaxf(ax, -M_CLAMP_), M_CLAMP_);
        ay = fminf(fmaxf(ay, -M_CLAMP_), M_CLAMP_);
        unsigned int pk = (unsigned int)f2bf(ax) | ((unsigned int)f2bf(ay) << 16);
        *(unsigned int*)(Mb + ((size_t)r * KADJ + k) * DDIM + feat) = pk;
    }
}

// ------- fused alpha + Y + pairnorm partial reduction (grid-stride, 512 blocks) -------
__global__ __launch_bounds__(256) void fuse_kernel(
    const unsigned short* __restrict__ Mb, const float* __restrict__ scores,
    const float* __restrict__ mask, const float* __restrict__ H,
    float* __restrict__ Y, float* __restrict__ alpha_out, float* __restrict__ red, int N)
{
    int tid = threadIdx.x;
    int sub = tid >> 6;              // node within 4-node tile
    int j = tid & 63;
    int dd = j * 2;                  // this thread's fixed d pair
    float csx = 0.f, csy = 0.f, sq = 0.f;

    for (int t = blockIdx.x; t < N / 4; t += gridDim.x) {
        int n = t * 4 + sub;
        float a[KADJ];
        float mx = -1e30f;
#pragma unroll
        for (int k = 0; k < KADJ; k++) {
            a[k] = scores[(size_t)n * KADJ + k] * (1.0f / TEMP_);
            mx = fmaxf(mx, a[k]);
        }
        float sum = 0.f;
#pragma unroll
        for (int k = 0; k < KADJ; k++) { a[k] = expf(a[k] - mx); sum += a[k]; }
#pragma unroll
        for (int k = 0; k < KADJ; k++) a[k] = (a[k] / sum) * mask[(size_t)n * KADJ + k];
        float s2 = 0.f;
#pragma unroll
        for (int k = 0; k < KADJ; k++) s2 += a[k];
        float inv = 1.f / fmaxf(s2, 1e-12f);
#pragma unroll
        for (int k = 0; k < KADJ; k++) a[k] = fmaxf(a[k] * inv, 1e-8f);
        s2 = 0.f;
#pragma unroll
        for (int k = 0; k < KADJ; k++) s2 += a[k];
        inv = 1.f / fmaxf(s2, 1e-12f);
#pragma unroll
        for (int k = 0; k < KADJ; k++) a[k] *= inv;

        float2 h = *(const float2*)(H + (size_t)n * DDIM + dd);
        float yx = h.x, yy = h.y;
#pragma unroll
        for (int k = 0; k < KADJ; k++) {
            unsigned int u = *(const unsigned int*)(Mb + ((size_t)n * KADJ + k) * DDIM + dd);
            yx += a[k] * bflo(u);
            yy += a[k] * bfhi(u);
        }
        *(float2*)(Y + (size_t)n * DDIM + dd) = make_float2(yx, yy);
        if (j < KADJ) alpha_out[(size_t)n * KADJ + j] = a[j];
        csx += yx; csy += yy;
        sq += yx * yx + yy * yy;
    }

    __shared__ float sx[256], sy[256], sq_[256];
    sx[tid] = csx; sy[tid] = csy; sq_[tid] = sq;
    __syncthreads();
    if (tid < 64) {
        float ax = sx[tid] + sx[tid + 64] + sx[tid + 128] + sx[tid + 192];
        float ay = sy[tid] + sy[tid + 64] + sy[tid + 128] + sy[tid + 192];
        atomicAdd(&red[tid * 2], ax);
        atomicAdd(&red[tid * 2 + 1], ay);
    }
    for (int s = 128; s > 0; s >>= 1) {
        if (tid < s) sq_[tid] += sq_[tid + s];
        __syncthreads();
    }
    if (tid == 0) atomicAdd(&red[128], sq_[0]);
}

// ---------------- pairnorm apply: writes H fp32 + Hb bf16 ----------
__global__ __launch_bounds__(256) void pairnorm_kernel(
    const float* __restrict__ Y, const float* __restrict__ red,
    float* __restrict__ Hout, unsigned short* __restrict__ Hb, int N)
{
    int tid = threadIdx.x;
    int d = tid & 127;
    float invN = 1.0f / (float)N;
    float mu = red[d] * invN;
    __shared__ float smu2[128];
    if (tid < 128) smu2[tid] = mu * mu;
    __syncthreads();
    for (int s = 64; s > 0; s >>= 1) {
        if (tid < s) smu2[tid] += smu2[tid + s];
        __syncthreads();
    }
    float summu2 = smu2[0];
    float var = red[128] * invN - summu2;
    float norm = sqrtf(fmaxf(var, 0.f)) + 1e-6f;
    float inv = 1.0f / norm;
    int n = blockIdx.x * 2 + (tid >> 7);
    if (n < N) {
        float v = (Y[(size_t)n * DDIM + d] - mu) * inv;
        v = fmaxf(v, 0.f);
        Hout[(size_t)n * DDIM + d] = v;
        Hb[(size_t)n * DDIM + d] = f2bf(v);
    }
}

extern "C" void kernel_launch(void* const* d_in, const int* in_sizes, int n_in,
                              void* d_out, int out_size, void* d_ws, size_t ws_size,
                              hipStream_t stream)
{
    const float* X      = (const float*)d_in[0];
    const int*   rows   = (const int*)d_in[1];
    const int*   cols   = (const int*)d_in[2];
    const float* mask   = (const float*)d_in[3];
    const float* logdeg = (const float*)d_in[4];
    const float* W_in0  = (const float*)d_in[5];
    const float* b_in0  = (const float*)d_in[6];
    const float* W_in1  = (const float*)d_in[7];
    const float* b_in1  = (const float*)d_in[8];
    const float* W_in2  = (const float*)d_in[9];
    const float* b_in2  = (const float*)d_in[10];
    const float* Wmsg[2] = {(const float*)d_in[11], (const float*)d_in[16]};
    const float* Wg1[2]  = {(const float*)d_in[12], (const float*)d_in[17]};
    const float* bg1[2]  = {(const float*)d_in[13], (const float*)d_in[18]};
    const float* Wg2[2]  = {(const float*)d_in[14], (const float*)d_in[19]};
    const float* bg2[2]  = {(const float*)d_in[15], (const float*)d_in[20]};
    const float* Wh1 = (const float*)d_in[21];
    const float* bh1 = (const float*)d_in[22];
    const float* Wh2 = (const float*)d_in[23];
    const float* bh2 = (const float*)d_in[24];

    // workspace layout (float slots), ~85 MB
    float* ws = (float*)d_ws;
    unsigned short* Xb  = (unsigned short*)ws;
    unsigned short* Mb  = (unsigned short*)ws;
    float* Ybuf  = ws + 5120000;
    float* GH    = ws + 7680000;
    uint2* staging = (uint2*)(ws + 10240000);       // NCOARSE*ESTRIDE*2 = 3,145,728 slots
    unsigned short* H0b = (unsigned short*)(ws + 10240000);
    unsigned short* H1b = (unsigned short*)(ws + 12800000);
    unsigned short* Zb  = (unsigned short*)(ws + 12800000);
    float* H     = ws + 15360000;                   // 2.56M
    unsigned short* Hb = (unsigned short*)(ws + 17920000);  // 1.28M slots
    float* scores = ws + 19200000;                  // 80000
    int*   offs   = (int*)(ws + 19280000);          // 80000
    int*   ends   = (int*)(ws + 19360000);          // 80000
    int*   edst   = (int*)(ws + 19440000);          // NCOARSE*ESTRIDE = 1,572,864
    float* red    = ws + 21012864;                  // 256
    int*   bcnt   = (int*)(ws + 21013120);          // 128
    unsigned short* w0t  = (unsigned short*)(ws + 21013248);  // 131072 slots
    unsigned short* w1t  = (unsigned short*)(ws + 21144320);  // 32768
    unsigned short* w2t  = (unsigned short*)(ws + 21177088);  // 16384
    unsigned short* wzg[2]  = {(unsigned short*)(ws + 21193472), (unsigned short*)(ws + 21209856)};  // 256x128 each
    unsigned short* wgmt[2] = {(unsigned short*)(ws + 21226240), (unsigned short*)(ws + 21234432)};
    unsigned short* wh1t = (unsigned short*)(ws + 21242624);
    float* logits = (float*)d_out;
    float* alpha_out = (float*)d_out + N_NODES;

    dim3 blk(256);
    int gM = (N_NODES + 127) / 128;     // 157

    // ---- CSR build ----
    (void)hipMemsetAsync(bcnt, 0, NCOARSE * sizeof(int), stream);
    binA2_kernel<<<BINA_NB, blk, 0, stream>>>(rows, cols, bcnt, staging);
    binB2_kernel<<<NCOARSE, blk, 0, stream>>>(staging, bcnt, offs, ends, edst);

    // ---- weight transposes + X cast ----
    TD10 descs;
    descs.d[0] = {W_in0, w0t, IN_DIM_, H_IN_};
    descs.d[1] = {W_in1, w1t, H_IN_, H_IN_};
    descs.d[2] = {W_in2, w2t, H_IN_, DDIM};
    descs.d[3] = {Wmsg[0], wzg[0], DDIM, DDIM};                           // rows 0-127 of wzg0
    descs.d[4] = {Wg1[0], wzg[0] + DDIM * DDIM, DDIM, GATE_H_};           // rows 128-255 of wzg0
    descs.d[5] = {Wmsg[1], wzg[1], DDIM, DDIM};
    descs.d[6] = {Wg1[1], wzg[1] + DDIM * DDIM, DDIM, GATE_H_};
    descs.d[7] = {Wg1[0] + DDIM * GATE_H_, wgmt[0], DDIM, GATE_H_};
    descs.d[8] = {Wg1[1] + DDIM * GATE_H_, wgmt[1], DDIM, GATE_H_};
    descs.d[9] = {Wh1, wh1t, DDIM, DDIM};
    transpose_all_kernel<<<dim3(8, 32, 10), blk, 0, stream>>>(descs);
    cast_bf16_kernel<<<N_NODES * IN_DIM_ / 8 / 256, blk, 0, stream>>>(X, Xb, N_NODES * IN_DIM_);

    // ---- encoder ----
    gemm_async_kernel<<<dim3(2, gM), blk, 0, stream>>>(Xb, w0t, b_in0, nullptr, H0b, N_NODES, H_IN_, IN_DIM_, 1);
    gemm_async_kernel<<<dim3(2, gM), blk, 0, stream>>>(H0b, w1t, b_in1, nullptr, H1b, N_NODES, H_IN_, H_IN_, 1);
    gemm_async_kernel<<<dim3(1, gM), blk, 0, stream>>>(H1b, w2t, b_in2, H, Hb, N_NODES, DDIM, H_IN_, 1);

    for (int b = 0; b < 2; b++) {
        // fused Z + GH GEMM
        zg_gemm_kernel<<<dim3(2, gM), blk, 0, stream>>>(Hb, wzg[b], bg1[b], Zb, GH, N_NODES);
        // gather: two feature-half passes (each pass's Zb working set = 2.56MB, L2-resident)
        gather_kernel<<<CSR_TOTAL / 4, blk, 0, stream>>>(offs, ends, edst, Zb, Mb, 0);
        gather_kernel<<<CSR_TOTAL / 4, blk, 0, stream>>>(offs, ends, edst, Zb, Mb, 1);
        gate_gemm_kernel<<<CSR_TOTAL / 128, blk, 0, stream>>>(Mb, wgmt[b], GH, logdeg,
                                                              Wg1[b] + 256 * GATE_H_, Wg2[b], bg2[b], scores);
        float* alph = alpha_out + (size_t)b * N_NODES * KADJ;
        (void)hipMemsetAsync(red, 0, 129 * sizeof(float), stream);
        fuse_kernel<<<512, blk, 0, stream>>>(Mb, scores, mask, H, Ybuf, alph, red, N_NODES);
        pairnorm_kernel<<<(N_NODES + 1) / 2, blk, 0, stream>>>(Ybuf, red, H, Hb, N_NODES);
    }

    // head (+ fused logits)
    head_gemm_kernel<<<gM, blk, 0, stream>>>(Hb, wh1t, bh1, Wh2, bh2, logits, N_NODES);
}